// Round 1
// baseline (674.784 us; speedup 1.0000x reference)
//
#include <hip/hip_runtime.h>

#define NIMG 16
#define CI   128
#define CO   256
#define HH   128
#define WW   128

typedef short bf16x8 __attribute__((ext_vector_type(8)));
typedef float f32x4  __attribute__((ext_vector_type(4)));

__device__ __forceinline__ unsigned short f2bf(float f) {
    unsigned u = __builtin_bit_cast(unsigned, f);
    unsigned r = u + 0x7fffu + ((u >> 16) & 1u);   // RNE
    return (unsigned short)(r >> 16);
}

// ---------------------------------------------------------------------------
// Prep 1: weights OIHW fp32 -> wt[tap][co][ci] bf16, scaled by kx[i]*kx[j]
// ---------------------------------------------------------------------------
__global__ void xform_w(const float* __restrict__ wsrc, unsigned short* __restrict__ wt) {
    int idx = blockIdx.x * 256 + threadIdx.x;       // (tap*256 + o)*128 + ci, 294912 total
    int ci   = idx & 127;
    int rest = idx >> 7;
    int o    = rest & 255;
    int tap  = rest >> 8;
    int i = tap / 3, j = tap - 3 * i;
    const float s0 = 0.7f;
    float si = (i == 1) ? 1.0f : s0;
    float sj = (j == 1) ? 1.0f : s0;
    float v = wsrc[((o * 128 + ci) * 3 + i) * 3 + j] * si * sj;
    wt[idx] = f2bf(v);
}

// ---------------------------------------------------------------------------
// Prep 2: x NCHW fp32 -> xt NHWC bf16  (per-block: one (n,h) row, LDS transpose)
// ---------------------------------------------------------------------------
__global__ __launch_bounds__(256) void xform_x(const float* __restrict__ x,
                                               unsigned short* __restrict__ xt) {
    int nh = blockIdx.x;                 // n*128 + h
    int n = nh >> 7, h = nh & 127;
    int t = threadIdx.x;
    __shared__ __align__(16) unsigned short ls[128][136];   // [w][c], pad 8 -> 16B-aligned rows

    int w  = t & 127;
    int ch = t >> 7;
    for (int cc = 0; cc < 64; ++cc) {
        int c = cc * 2 + ch;
        float v = x[(((size_t)n * CI + c) * HH + h) * WW + w];
        ls[w][c] = f2bf(v);
    }
    __syncthreads();
    size_t obase = (size_t)nh * WW * CI;           // element base of (n,h,0,0)
    for (int it = 0; it < 8; ++it) {
        int chunk = it * 256 + t;                  // 0..2047, 16B each
        int ww = chunk >> 4, cp = chunk & 15;
        int4 v = *(const int4*)&ls[ww][cp * 8];
        *(int4*)((char*)(xt + obase) + (size_t)chunk * 16) = v;
    }
}

// ---------------------------------------------------------------------------
// Main: implicit-GEMM conv. Tile 128 pixels (one (n,h) row) x 128 co.
// K-loop: 4 ci-chunks of 32; per chunk stage 3x130-pixel halo into LDS,
// then 9 shifted-window taps of mfma_f32_16x16x32_bf16 (4x4 frags/wave).
// ---------------------------------------------------------------------------
__global__ __launch_bounds__(256) void conv_mfma(const unsigned short* __restrict__ xt,
                                                 const unsigned short* __restrict__ wt,
                                                 const float* __restrict__ bias,
                                                 float* __restrict__ out) {
    int bid = blockIdx.x;
    int bn  = bid & 1;            // co half (0/1)
    int bm  = bid >> 1;           // (n,h)
    int n = bm >> 7, h = bm & 127;
    int tid  = threadIdx.x;
    int lane = tid & 63, wv = tid >> 6;
    int mw = wv & 1, nw = wv >> 1;
    int lr = lane & 15;           // frag row index (m for A, n for B, col for C)
    int lq = lane >> 4;           // quad

    __shared__ __align__(16) unsigned short xs[3 * 130 * 32];   // [dh][wp][ci32]
    __shared__ __align__(16) float es[4][16][68];               // per-wave epilogue

    f32x4 acc[4][4];
    const f32x4 zero = {0.0f, 0.0f, 0.0f, 0.0f};
    for (int mi = 0; mi < 4; ++mi)
        for (int ni = 0; ni < 4; ++ni) acc[mi][ni] = zero;

    // per-lane invariants
    int am[4];                    // LDS elem offset for A frags (pixel part)
    for (int mi = 0; mi < 4; ++mi) am[mi] = (mw * 64 + mi * 16 + lr) * 32 + lq * 8;
    size_t bo[4];                 // wt elem offset per ni (minus tap/kc parts)
    for (int ni = 0; ni < 4; ++ni) {
        int co = bn * 128 + nw * 64 + ni * 16 + lr;
        bo[ni] = (size_t)co * CI + lq * 8;
    }

    const size_t rowstride = (size_t)WW * CI;     // elems per image row in xt

#pragma unroll 1
    for (int kc = 0; kc < 4; ++kc) {
        __syncthreads();
        // stage: 3*130 pixels x 32 ci (bf16) = 1560 chunks of 16B
        for (int c = tid; c < 1560; c += 256) {
            int dh = c / 520;
            int rem = c - dh * 520;
            int wp = rem >> 2, part = rem & 3;
            int r = h + dh - 1, wsrc = wp - 1;
            int4 v = make_int4(0, 0, 0, 0);
            if ((unsigned)r < 128u && (unsigned)wsrc < 128u) {
                v = *(const int4*)(xt + ((size_t)(n * HH + r) * WW + wsrc) * CI
                                   + kc * 32 + part * 8);
            }
            *(int4*)(xs + (dh * 130 + wp) * 32 + part * 8) = v;
        }
        __syncthreads();

        const unsigned short* wk = wt + kc * 32;
#pragma unroll
        for (int tap = 0; tap < 9; ++tap) {
            int di = tap / 3, dj = tap - 3 * di;
            bf16x8 a[4], b[4];
            int abase = di * (130 * 32) + dj * 32;
#pragma unroll
            for (int mi = 0; mi < 4; ++mi)
                a[mi] = *(const bf16x8*)(xs + abase + am[mi]);
            const unsigned short* wtap = wk + (size_t)tap * CO * CI;
#pragma unroll
            for (int ni = 0; ni < 4; ++ni)
                b[ni] = *(const bf16x8*)(wtap + bo[ni]);
#pragma unroll
            for (int mi = 0; mi < 4; ++mi)
#pragma unroll
                for (int ni = 0; ni < 4; ++ni)
                    acc[mi][ni] = __builtin_amdgcn_mfma_f32_16x16x32_bf16(
                        a[mi], b[ni], acc[mi][ni], 0, 0, 0);
        }
    }

    // epilogue: LDS transpose -> coalesced NCHW stores (+bias)
    for (int ni = 0; ni < 4; ++ni) {
        __syncthreads();
        for (int mi = 0; mi < 4; ++mi) {
            // C/D: col(co)=lane&15, row(pixel)=(lane>>4)*4+reg
            *(float4*)&es[wv][lr][mi * 16 + lq * 4] =
                *(const float4*)&acc[mi][ni];
        }
        __syncthreads();
        int row = lane >> 2;      // co-local 0..15
        int cp  = lane & 3;       // w chunk
        int co = bn * 128 + nw * 64 + ni * 16 + row;
        float bco = bias[co];
        size_t obase = (((size_t)n * CO + co) * HH + h) * WW + mw * 64 + cp * 16;
#pragma unroll
        for (int q = 0; q < 4; ++q) {
            float4 tv = *(const float4*)&es[wv][row][cp * 16 + q * 4];
            tv.x += bco; tv.y += bco; tv.z += bco; tv.w += bco;
            *(float4*)(out + obase + q * 4) = tv;
        }
    }
}

// ---------------------------------------------------------------------------
// Fallback: direct fp32 conv (only if workspace too small)
// ---------------------------------------------------------------------------
__global__ void conv_direct(const float* __restrict__ x, const float* __restrict__ wsrc,
                            const float* __restrict__ bias, float* __restrict__ out) {
    int b = blockIdx.x;           // ((n*256+o)*128 + h)
    int w = threadIdx.x;
    int h = b & 127;
    int rest = b >> 7;
    int o = rest & 255, n = rest >> 8;
    const float s[3] = {0.7f, 1.0f, 0.7f};
    float acc = bias[o];
    for (int ci = 0; ci < 128; ++ci) {
        const float* xp = x + ((size_t)n * CI + ci) * HH * WW;
        const float* wp = wsrc + ((size_t)o * CI + ci) * 9;
        for (int i = 0; i < 3; ++i) {
            int r = h + i - 1;
            if ((unsigned)r >= 128u) continue;
            for (int j = 0; j < 3; ++j) {
                int c = w + j - 1;
                if ((unsigned)c >= 128u) continue;
                acc += xp[r * 128 + c] * wp[i * 3 + j] * s[i] * s[j];
            }
        }
    }
    out[(size_t)b * 128 + w] = acc;
}

extern "C" void kernel_launch(void* const* d_in, const int* in_sizes, int n_in,
                              void* d_out, int out_size, void* d_ws, size_t ws_size,
                              hipStream_t stream) {
    const float* x    = (const float*)d_in[0];
    const float* wsrc = (const float*)d_in[1];
    const float* bias = (const float*)d_in[2];
    float* out = (float*)d_out;

    const size_t wt_bytes = (size_t)9 * CO * CI * 2;              // 589,824
    const size_t xt_bytes = (size_t)NIMG * HH * WW * CI * 2;      // 67,108,864
    if (ws_size < wt_bytes + xt_bytes) {
        conv_direct<<<NIMG * CO * HH, 128, 0, stream>>>(x, wsrc, bias, out);
        return;
    }
    unsigned short* wt = (unsigned short*)d_ws;
    unsigned short* xt = (unsigned short*)((char*)d_ws + wt_bytes);

    xform_w<<<(9 * CO * CI) / 256, 256, 0, stream>>>(wsrc, wt);
    xform_x<<<NIMG * HH, 256, 0, stream>>>(x, xt);
    conv_mfma<<<NIMG * HH * 2, 256, 0, stream>>>(xt, wt, bias, out);
}